// Round 1
// baseline (672.584 us; speedup 1.0000x reference)
//
#include <hip/hip_runtime.h>
#include <math.h>

#define NN 25000
#define NE 400000
#define HH 128
#define NH (NN*HH)
#define NB 16
#define EB 64

// gaussian smearing: offset_k = k*8/15, coeff = -0.5/(8/15)^2 = -1.7578125
#define GS_STEP  (8.0f/15.0f)
#define GS_COEFF (-1.7578125f)

// ---------------- node embedding: h = x @ node_w + node_b ----------------
__global__ __launch_bounds__(256) void k_node_embed(
    const float* __restrict__ x, const float* __restrict__ w,
    const float* __restrict__ b, float* __restrict__ h) {
  int t = blockIdx.x * 256 + threadIdx.x;
  if (t >= NH) return;
  int n = t >> 7, j = t & 127;
  const float* xr = x + n * 6;
  float acc = b[j];
#pragma unroll
  for (int k = 0; k < 6; ++k) acc = fmaf(xr[k], w[k * HH + j], acc);
  h[t] = acc;
}

// ---------------- per-node projections ----------------
// PD[n][j]      = fb[j] + h[n] @ fw[0:128]     (dst part of lin_f)
// PS[n][j]      =         h[n] @ fw[128:256]   (src part of lin_f)
// PD[n][128+j]  = sb[j] + h[n] @ sw[0:128]     (dst part of lin_s)
// PS[n][128+j]  =         h[n] @ sw[128:256]   (src part of lin_s)
__global__ __launch_bounds__(512) void k_proj(
    const float* __restrict__ h,
    const float* __restrict__ fw, const float* __restrict__ sw,
    const float* __restrict__ fb, const float* __restrict__ sb,
    float* __restrict__ PD, float* __restrict__ PS) {
  __shared__ float hs[NB * HH];
  const int tid = threadIdx.x;
  const int n0 = blockIdx.x * NB;
#pragma unroll
  for (int i = tid; i < NB * HH; i += 512) {
    int ln = i >> 7, k = i & 127;
    int n = n0 + ln;
    hs[ln * HH + k] = (n < NN) ? h[n * HH + k] : 0.f;
  }
  __syncthreads();
  const int p = tid >> 7;      // 0: f-dst, 1: f-src, 2: s-dst, 3: s-src
  const int j = tid & 127;
  const float* wb = ((p & 2) ? sw : fw) + ((p & 1) ? HH * HH : 0) + j;
  float acc[NB];
#pragma unroll
  for (int i = 0; i < NB; ++i) acc[i] = 0.f;
  for (int k0 = 0; k0 < HH; k0 += 4) {
    float w0 = wb[(k0 + 0) * HH];
    float w1 = wb[(k0 + 1) * HH];
    float w2 = wb[(k0 + 2) * HH];
    float w3 = wb[(k0 + 3) * HH];
#pragma unroll
    for (int i = 0; i < NB; ++i) {
      const float4 v = *(const float4*)(hs + i * HH + k0);
      acc[i] = fmaf(v.x, w0, acc[i]);
      acc[i] = fmaf(v.y, w1, acc[i]);
      acc[i] = fmaf(v.z, w2, acc[i]);
      acc[i] = fmaf(v.w, w3, acc[i]);
    }
  }
  const float bias = (p == 0) ? fb[j] : (p == 2) ? sb[j] : 0.f;
  float* outp = (p & 1) ? PS : PD;
  const int col = j + ((p >> 1) << 7);
#pragma unroll
  for (int i = 0; i < NB; ++i) {
    int n = n0 + i;
    if (n < NN) outp[n * 256 + col] = acc[i] + bias;
  }
}

// ---------------- edge kernel: msg = sigmoid(f)*softplus(s), atomic agg ----------------
__global__ __launch_bounds__(256) void k_edge(
    const int* __restrict__ ei, const float* __restrict__ eattr,
    const float* __restrict__ fw3, const float* __restrict__ sw3,
    const float* __restrict__ PD, const float* __restrict__ PS,
    float* __restrict__ agg) {
  __shared__ float w3s[2 * 16 * HH];  // 16KB: fw3 then sw3
  __shared__ float es[EB][16];        // gaussian features for this block's edges
  const int tid = threadIdx.x;
  for (int i = tid; i < 16 * HH; i += 256) {
    w3s[i] = fw3[i];
    w3s[16 * HH + i] = sw3[i];
  }
  const int e0 = blockIdx.x * EB;
  for (int i = tid; i < EB * 16; i += 256) {
    int le = i >> 4, k = i & 15;
    float d = eattr[e0 + le];
    float t = d - (float)k * GS_STEP;
    es[le][k] = __expf(GS_COEFF * t * t);
  }
  __syncthreads();
  const int half = tid >> 7;  // which of 2 edges this iteration
  const int j = tid & 127;    // channel
  for (int it = 0; it < EB / 2; ++it) {
    const int le = 2 * it + half;
    const int e = e0 + le;
    const int src = ei[e];
    const int dst = ei[NE + e];
    float f = PD[dst * 256 + j] + PS[src * 256 + j];
    float s = PD[dst * 256 + 128 + j] + PS[src * 256 + 128 + j];
#pragma unroll
    for (int k = 0; k < 16; ++k) {
      const float ek = es[le][k];
      f = fmaf(ek, w3s[k * HH + j], f);
      s = fmaf(ek, w3s[16 * HH + k * HH + j], s);
    }
    const float sig = 1.f / (1.f + __expf(-f));
    const float sp = fmaxf(s, 0.f) + log1pf(__expf(-fabsf(s)));
    atomicAdd(&agg[dst * HH + j], sig * sp);
  }
}

// ---------------- per-channel sum / sumsq ----------------
__global__ __launch_bounds__(256) void k_stats(
    const float* __restrict__ agg, float* __restrict__ stats) {
  const int c = threadIdx.x & 127;
  const int slice = (blockIdx.x * 256 + threadIdx.x) >> 7;
  const int nslices = (gridDim.x * 256) >> 7;
  float s = 0.f, s2 = 0.f;
  for (int n = slice; n < NN; n += nslices) {
    float v = agg[n * HH + c];
    s += v;
    s2 = fmaf(v, v, s2);
  }
  atomicAdd(&stats[c], s);
  atomicAdd(&stats[HH + c], s2);
}

// ---------------- batchnorm + residual + relu ----------------
__global__ __launch_bounds__(256) void k_bn(
    const float* __restrict__ agg, const float* __restrict__ hold,
    const float* __restrict__ stats, const float* __restrict__ g,
    const float* __restrict__ b, float* __restrict__ hnew) {
  int t = blockIdx.x * 256 + threadIdx.x;
  if (t >= NH) return;
  const int c = t & 127;
  const float inv_n = 1.f / (float)NN;
  const float mu = stats[c] * inv_n;
  const float var = stats[HH + c] * inv_n - mu * mu;
  const float rs = rsqrtf(var + 1e-5f);
  const float v = (agg[t] - mu) * rs * g[c] + b[c] + hold[t];
  hnew[t] = fmaxf(v, 0.f);
}

// ---------------- final fc: out = h @ fc_w + fc_b ----------------
__global__ __launch_bounds__(64) void k_fc(
    const float* __restrict__ h, const float* __restrict__ w,
    const float* __restrict__ b, float* __restrict__ out) {
  const int ln = threadIdx.x >> 5;
  const int m = threadIdx.x & 31;
  const int n = blockIdx.x * 2 + ln;
  if (n >= NN || m >= 21) return;
  const float* hr = h + n * HH;
  float acc = b[m];
#pragma unroll 4
  for (int k = 0; k < HH; ++k) acc = fmaf(hr[k], w[k * 21 + m], acc);
  out[n * 21 + m] = acc;
}

extern "C" void kernel_launch(void* const* d_in, const int* in_sizes, int n_in,
                              void* d_out, int out_size, void* d_ws, size_t ws_size,
                              hipStream_t stream) {
  const float* x      = (const float*)d_in[0];
  const float* eattr  = (const float*)d_in[1];
  const float* node_w = (const float*)d_in[2];
  const float* node_b = (const float*)d_in[3];
  const float* f1w    = (const float*)d_in[4];
  const float* f1b    = (const float*)d_in[5];
  const float* s1w    = (const float*)d_in[6];
  const float* s1b    = (const float*)d_in[7];
  const float* bn1g   = (const float*)d_in[8];
  const float* bn1b   = (const float*)d_in[9];
  const float* f2w    = (const float*)d_in[10];
  const float* f2b    = (const float*)d_in[11];
  const float* s2w    = (const float*)d_in[12];
  const float* s2b    = (const float*)d_in[13];
  const float* bn2g   = (const float*)d_in[14];
  const float* bn2b   = (const float*)d_in[15];
  const float* fcw    = (const float*)d_in[16];
  const float* fcb    = (const float*)d_in[17];
  const int*   ei     = (const int*)d_in[18];
  float* out = (float*)d_out;

  float* ws   = (float*)d_ws;
  float* bufA = ws;            // h (layer input), later agg2/h2
  float* bufB = ws + NH;       // agg1 -> h1
  float* PD   = ws + 2 * (size_t)NH;  // [NN][256]
  float* PS   = ws + 4 * (size_t)NH;  // [NN][256]
  float* stats = ws + 6 * (size_t)NH; // 256 floats

  const int g_embed = (NH + 255) / 256;
  const int g_proj  = (NN + NB - 1) / NB;
  const int g_edge  = NE / EB;
  const int g_bn    = (NH + 255) / 256;

  // h0 = x @ node_w + node_b
  k_node_embed<<<g_embed, 256, 0, stream>>>(x, node_w, node_b, bufA);

  // ---- layer 1 ----
  k_proj<<<g_proj, 512, 0, stream>>>(bufA, f1w, s1w, f1b, s1b, PD, PS);
  hipMemsetAsync(bufB, 0, (size_t)NH * 4, stream);
  hipMemsetAsync(stats, 0, 256 * 4, stream);
  k_edge<<<g_edge, 256, 0, stream>>>(ei, eattr, f1w + 256 * HH, s1w + 256 * HH,
                                     PD, PS, bufB);
  k_stats<<<256, 256, 0, stream>>>(bufB, stats);
  k_bn<<<g_bn, 256, 0, stream>>>(bufB, bufA, stats, bn1g, bn1b, bufB);

  // ---- layer 2 ----
  k_proj<<<g_proj, 512, 0, stream>>>(bufB, f2w, s2w, f2b, s2b, PD, PS);
  hipMemsetAsync(bufA, 0, (size_t)NH * 4, stream);
  hipMemsetAsync(stats, 0, 256 * 4, stream);
  k_edge<<<g_edge, 256, 0, stream>>>(ei, eattr, f2w + 256 * HH, s2w + 256 * HH,
                                     PD, PS, bufA);
  k_stats<<<256, 256, 0, stream>>>(bufA, stats);
  k_bn<<<g_bn, 256, 0, stream>>>(bufA, bufB, stats, bn2g, bn2b, bufA);

  // ---- final fc ----
  k_fc<<<(NN + 1) / 2, 64, 0, stream>>>(bufA, fcw, fcb, out);
}

// Round 2
// 651.855 us; speedup vs baseline: 1.0318x; 1.0318x over previous
//
#include <hip/hip_runtime.h>
#include <math.h>

#define NN 25000
#define NE 400000
#define HH 128
#define NH (NN*HH)
#define NB 16
#define EB 64

// gaussian smearing: offset_k = k*8/15, coeff = -0.5/(8/15)^2 = -1.7578125
#define GS_STEP  (8.0f/15.0f)
#define GS_COEFF (-1.7578125f)

// ---------------- node embedding: h = x @ node_w + node_b ----------------
__global__ __launch_bounds__(256) void k_node_embed(
    const float* __restrict__ x, const float* __restrict__ w,
    const float* __restrict__ b, float* __restrict__ h) {
  int t = blockIdx.x * 256 + threadIdx.x;
  if (t >= NH) return;
  int n = t >> 7, j = t & 127;
  const float* xr = x + n * 6;
  float acc = b[j];
#pragma unroll
  for (int k = 0; k < 6; ++k) acc = fmaf(xr[k], w[k * HH + j], acc);
  h[t] = acc;
}

// ---------------- per-node projections ----------------
// Interleaved layout: PD[n][2j]   = fb[j] + h[n] @ fw[0:128]_col_j   (f, dst)
//                     PD[n][2j+1] = sb[j] + h[n] @ sw[0:128]_col_j   (s, dst)
//                     PS[n][2j]   =         h[n] @ fw[128:256]_col_j (f, src)
//                     PS[n][2j+1] =         h[n] @ sw[128:256]_col_j (s, src)
__global__ __launch_bounds__(512) void k_proj(
    const float* __restrict__ h,
    const float* __restrict__ fw, const float* __restrict__ sw,
    const float* __restrict__ fb, const float* __restrict__ sb,
    float* __restrict__ PD, float* __restrict__ PS) {
  __shared__ float hs[NB * HH];
  const int tid = threadIdx.x;
  const int n0 = blockIdx.x * NB;
#pragma unroll
  for (int i = tid; i < NB * HH; i += 512) {
    int ln = i >> 7, k = i & 127;
    int n = n0 + ln;
    hs[ln * HH + k] = (n < NN) ? h[n * HH + k] : 0.f;
  }
  __syncthreads();
  const int p = tid >> 7;      // 0: f-dst, 1: f-src, 2: s-dst, 3: s-src
  const int j = tid & 127;
  const float* wb = ((p & 2) ? sw : fw) + ((p & 1) ? HH * HH : 0) + j;
  float acc[NB];
#pragma unroll
  for (int i = 0; i < NB; ++i) acc[i] = 0.f;
  for (int k0 = 0; k0 < HH; k0 += 4) {
    float w0 = wb[(k0 + 0) * HH];
    float w1 = wb[(k0 + 1) * HH];
    float w2 = wb[(k0 + 2) * HH];
    float w3 = wb[(k0 + 3) * HH];
#pragma unroll
    for (int i = 0; i < NB; ++i) {
      const float4 v = *(const float4*)(hs + i * HH + k0);
      acc[i] = fmaf(v.x, w0, acc[i]);
      acc[i] = fmaf(v.y, w1, acc[i]);
      acc[i] = fmaf(v.z, w2, acc[i]);
      acc[i] = fmaf(v.w, w3, acc[i]);
    }
  }
  const float bias = (p == 0) ? fb[j] : (p == 2) ? sb[j] : 0.f;
  float* outp = (p & 1) ? PS : PD;
  const int col = 2 * j + (p >> 1);   // interleave f/s per channel
#pragma unroll
  for (int i = 0; i < NB; ++i) {
    int n = n0 + i;
    if (n < NN) outp[n * 256 + col] = acc[i] + bias;
  }
}

// ---------------- edge kernel: msg = sigmoid(f)*softplus(s), atomic agg ----------------
__global__ __launch_bounds__(256) void k_edge(
    const int* __restrict__ ei, const float* __restrict__ eattr,
    const float* __restrict__ fw3, const float* __restrict__ sw3,
    const float* __restrict__ PD, const float* __restrict__ PS,
    float* __restrict__ agg) {
  __shared__ float es[EB][16];   // gaussian features, rows 64B -> float4 aligned
  __shared__ int2  sd[EB];       // (src, dst) per edge
  const int tid = threadIdx.x;
  const int j = tid & 127;       // channel

  // per-thread weight columns in registers (16 + 16 VGPRs)
  float wf[16], wsv[16];
#pragma unroll
  for (int k = 0; k < 16; ++k) {
    wf[k]  = fw3[k * HH + j];
    wsv[k] = sw3[k * HH + j];
  }

  const int e0 = blockIdx.x * EB;
  for (int i = tid; i < EB * 16; i += 256) {
    int le = i >> 4, k = i & 15;
    float d = eattr[e0 + le];
    float t = d - (float)k * GS_STEP;
    es[le][k] = __expf(GS_COEFF * t * t);
  }
  if (tid < EB) sd[tid] = make_int2(ei[e0 + tid], ei[NE + e0 + tid]);
  __syncthreads();

  const int half = tid >> 7;  // which of 2 edges per iteration
  for (int it = 0; it < EB / 2; ++it) {
    const int le = 2 * it + half;
    const int2 se = sd[le];                       // b64 broadcast
    const float4 g0 = *(const float4*)&es[le][0]; // b128 broadcasts
    const float4 g1 = *(const float4*)&es[le][4];
    const float4 g2 = *(const float4*)&es[le][8];
    const float4 g3 = *(const float4*)&es[le][12];
    const float2 a = *(const float2*)&PD[se.y * 256 + 2 * j];
    const float2 b = *(const float2*)&PS[se.x * 256 + 2 * j];
    float f = a.x + b.x;
    float s = a.y + b.y;
    f = fmaf(g0.x, wf[0], f);  s = fmaf(g0.x, wsv[0], s);
    f = fmaf(g0.y, wf[1], f);  s = fmaf(g0.y, wsv[1], s);
    f = fmaf(g0.z, wf[2], f);  s = fmaf(g0.z, wsv[2], s);
    f = fmaf(g0.w, wf[3], f);  s = fmaf(g0.w, wsv[3], s);
    f = fmaf(g1.x, wf[4], f);  s = fmaf(g1.x, wsv[4], s);
    f = fmaf(g1.y, wf[5], f);  s = fmaf(g1.y, wsv[5], s);
    f = fmaf(g1.z, wf[6], f);  s = fmaf(g1.z, wsv[6], s);
    f = fmaf(g1.w, wf[7], f);  s = fmaf(g1.w, wsv[7], s);
    f = fmaf(g2.x, wf[8], f);  s = fmaf(g2.x, wsv[8], s);
    f = fmaf(g2.y, wf[9], f);  s = fmaf(g2.y, wsv[9], s);
    f = fmaf(g2.z, wf[10], f); s = fmaf(g2.z, wsv[10], s);
    f = fmaf(g2.w, wf[11], f); s = fmaf(g2.w, wsv[11], s);
    f = fmaf(g3.x, wf[12], f); s = fmaf(g3.x, wsv[12], s);
    f = fmaf(g3.y, wf[13], f); s = fmaf(g3.y, wsv[13], s);
    f = fmaf(g3.z, wf[14], f); s = fmaf(g3.z, wsv[14], s);
    f = fmaf(g3.w, wf[15], f); s = fmaf(g3.w, wsv[15], s);
    const float sig = 1.f / (1.f + __expf(-f));
    const float sp = fmaxf(s, 0.f) + log1pf(__expf(-fabsf(s)));
    atomicAdd(&agg[se.y * HH + j], sig * sp);
  }
}

// ---------------- per-channel sum / sumsq ----------------
__global__ __launch_bounds__(256) void k_stats(
    const float* __restrict__ agg, float* __restrict__ stats) {
  const int c = threadIdx.x & 127;
  const int slice = (blockIdx.x * 256 + threadIdx.x) >> 7;
  const int nslices = (gridDim.x * 256) >> 7;
  float s = 0.f, s2 = 0.f;
  for (int n = slice; n < NN; n += nslices) {
    float v = agg[n * HH + c];
    s += v;
    s2 = fmaf(v, v, s2);
  }
  atomicAdd(&stats[c], s);
  atomicAdd(&stats[HH + c], s2);
}

// ---------------- batchnorm + residual + relu ----------------
__global__ __launch_bounds__(256) void k_bn(
    const float* __restrict__ agg, const float* __restrict__ hold,
    const float* __restrict__ stats, const float* __restrict__ g,
    const float* __restrict__ b, float* __restrict__ hnew) {
  int t = blockIdx.x * 256 + threadIdx.x;
  if (t >= NH) return;
  const int c = t & 127;
  const float inv_n = 1.f / (float)NN;
  const float mu = stats[c] * inv_n;
  const float var = stats[HH + c] * inv_n - mu * mu;
  const float rs = rsqrtf(var + 1e-5f);
  const float v = (agg[t] - mu) * rs * g[c] + b[c] + hold[t];
  hnew[t] = fmaxf(v, 0.f);
}

// ---------------- final fc: out = h @ fc_w + fc_b ----------------
__global__ __launch_bounds__(64) void k_fc(
    const float* __restrict__ h, const float* __restrict__ w,
    const float* __restrict__ b, float* __restrict__ out) {
  const int ln = threadIdx.x >> 5;
  const int m = threadIdx.x & 31;
  const int n = blockIdx.x * 2 + ln;
  if (n >= NN || m >= 21) return;
  const float* hr = h + n * HH;
  float acc = b[m];
#pragma unroll 4
  for (int k = 0; k < HH; ++k) acc = fmaf(hr[k], w[k * 21 + m], acc);
  out[n * 21 + m] = acc;
}

extern "C" void kernel_launch(void* const* d_in, const int* in_sizes, int n_in,
                              void* d_out, int out_size, void* d_ws, size_t ws_size,
                              hipStream_t stream) {
  const float* x      = (const float*)d_in[0];
  const float* eattr  = (const float*)d_in[1];
  const float* node_w = (const float*)d_in[2];
  const float* node_b = (const float*)d_in[3];
  const float* f1w    = (const float*)d_in[4];
  const float* f1b    = (const float*)d_in[5];
  const float* s1w    = (const float*)d_in[6];
  const float* s1b    = (const float*)d_in[7];
  const float* bn1g   = (const float*)d_in[8];
  const float* bn1b   = (const float*)d_in[9];
  const float* f2w    = (const float*)d_in[10];
  const float* f2b    = (const float*)d_in[11];
  const float* s2w    = (const float*)d_in[12];
  const float* s2b    = (const float*)d_in[13];
  const float* bn2g   = (const float*)d_in[14];
  const float* bn2b   = (const float*)d_in[15];
  const float* fcw    = (const float*)d_in[16];
  const float* fcb    = (const float*)d_in[17];
  const int*   ei     = (const int*)d_in[18];
  float* out = (float*)d_out;

  float* ws   = (float*)d_ws;
  float* bufA = ws;            // h (layer input), later agg2/h2
  float* bufB = ws + NH;       // agg1 -> h1
  float* PD   = ws + 2 * (size_t)NH;  // [NN][256]
  float* PS   = ws + 4 * (size_t)NH;  // [NN][256]
  float* stats = ws + 6 * (size_t)NH; // 256 floats

  const int g_embed = (NH + 255) / 256;
  const int g_proj  = (NN + NB - 1) / NB;
  const int g_edge  = NE / EB;
  const int g_bn    = (NH + 255) / 256;

  // h0 = x @ node_w + node_b
  k_node_embed<<<g_embed, 256, 0, stream>>>(x, node_w, node_b, bufA);

  // ---- layer 1 ----
  k_proj<<<g_proj, 512, 0, stream>>>(bufA, f1w, s1w, f1b, s1b, PD, PS);
  hipMemsetAsync(bufB, 0, (size_t)NH * 4, stream);
  hipMemsetAsync(stats, 0, 256 * 4, stream);
  k_edge<<<g_edge, 256, 0, stream>>>(ei, eattr, f1w + 256 * HH, s1w + 256 * HH,
                                     PD, PS, bufB);
  k_stats<<<256, 256, 0, stream>>>(bufB, stats);
  k_bn<<<g_bn, 256, 0, stream>>>(bufB, bufA, stats, bn1g, bn1b, bufB);

  // ---- layer 2 ----
  k_proj<<<g_proj, 512, 0, stream>>>(bufB, f2w, s2w, f2b, s2b, PD, PS);
  hipMemsetAsync(bufA, 0, (size_t)NH * 4, stream);
  hipMemsetAsync(stats, 0, 256 * 4, stream);
  k_edge<<<g_edge, 256, 0, stream>>>(ei, eattr, f2w + 256 * HH, s2w + 256 * HH,
                                     PD, PS, bufA);
  k_stats<<<256, 256, 0, stream>>>(bufA, stats);
  k_bn<<<g_bn, 256, 0, stream>>>(bufA, bufB, stats, bn2g, bn2b, bufA);

  // ---- final fc ----
  k_fc<<<(NN + 1) / 2, 64, 0, stream>>>(bufA, fcw, fcb, out);
}

// Round 4
// 630.197 us; speedup vs baseline: 1.0673x; 1.0344x over previous
//
#include <hip/hip_runtime.h>
#include <math.h>

#define NN 25000
#define NE 400000
#define HH 128
#define NH (NN*HH)
#define NB 16
#define EB 64

// gaussian smearing: offset_k = k*8/15, coeff = -0.5/(8/15)^2 = -1.7578125
#define GS_STEP  (8.0f/15.0f)
#define GS_COEFF (-1.7578125f)
#define LOG2E    1.442695041f
#define LN2      0.6931471806f

typedef float f32x2 __attribute__((ext_vector_type(2)));

// ---------------- node embedding: h = x @ node_w + node_b ----------------
__global__ __launch_bounds__(256) void k_node_embed(
    const float* __restrict__ x, const float* __restrict__ w,
    const float* __restrict__ b, float* __restrict__ h) {
  int t = blockIdx.x * 256 + threadIdx.x;
  if (t >= NH) return;
  int n = t >> 7, j = t & 127;
  const float* xr = x + n * 6;
  float acc = b[j];
#pragma unroll
  for (int k = 0; k < 6; ++k) acc = fmaf(xr[k], w[k * HH + j], acc);
  h[t] = acc;
}

// ---------------- per-node projections ----------------
// Interleaved layout: PD[n][2j]   = fb[j] + h[n] @ fw[0:128]_col_j   (f, dst)
//                     PD[n][2j+1] = sb[j] + h[n] @ sw[0:128]_col_j   (s, dst)
//                     PS[n][2j]   =         h[n] @ fw[128:256]_col_j (f, src)
//                     PS[n][2j+1] =         h[n] @ sw[128:256]_col_j (s, src)
__global__ __launch_bounds__(512) void k_proj(
    const float* __restrict__ h,
    const float* __restrict__ fw, const float* __restrict__ sw,
    const float* __restrict__ fb, const float* __restrict__ sb,
    float* __restrict__ PD, float* __restrict__ PS) {
  __shared__ float hs[NB * HH];
  const int tid = threadIdx.x;
  const int n0 = blockIdx.x * NB;
#pragma unroll
  for (int i = tid; i < NB * HH; i += 512) {
    int ln = i >> 7, k = i & 127;
    int n = n0 + ln;
    hs[ln * HH + k] = (n < NN) ? h[n * HH + k] : 0.f;
  }
  __syncthreads();
  const int p = tid >> 7;      // 0: f-dst, 1: f-src, 2: s-dst, 3: s-src
  const int j = tid & 127;
  const float* wb = ((p & 2) ? sw : fw) + ((p & 1) ? HH * HH : 0) + j;
  float acc[NB];
#pragma unroll
  for (int i = 0; i < NB; ++i) acc[i] = 0.f;
  for (int k0 = 0; k0 < HH; k0 += 4) {
    float w0 = wb[(k0 + 0) * HH];
    float w1 = wb[(k0 + 1) * HH];
    float w2 = wb[(k0 + 2) * HH];
    float w3 = wb[(k0 + 3) * HH];
#pragma unroll
    for (int i = 0; i < NB; ++i) {
      const float4 v = *(const float4*)(hs + i * HH + k0);
      acc[i] = fmaf(v.x, w0, acc[i]);
      acc[i] = fmaf(v.y, w1, acc[i]);
      acc[i] = fmaf(v.z, w2, acc[i]);
      acc[i] = fmaf(v.w, w3, acc[i]);
    }
  }
  const float bias = (p == 0) ? fb[j] : (p == 2) ? sb[j] : 0.f;
  float* outp = (p & 1) ? PS : PD;
  const int col = 2 * j + (p >> 1);   // interleave f/s per channel
#pragma unroll
  for (int i = 0; i < NB; ++i) {
    int n = n0 + i;
    if (n < NN) outp[n * 256 + col] = acc[i] + bias;
  }
}

// ---------------- edge kernel: msg = sigmoid(f)*softplus(s), atomic agg ----------------
__global__ __launch_bounds__(256) void k_edge(
    const int* __restrict__ ei, const float* __restrict__ eattr,
    const float* __restrict__ fw3, const float* __restrict__ sw3,
    const float* __restrict__ PD, const float* __restrict__ PS,
    float* __restrict__ agg) {
  __shared__ float es[EB][16];   // gaussian features, rows 64B -> float4 aligned
  __shared__ int2  sd[EB];       // (src, dst) per edge
  const int tid = threadIdx.x;
  const int j = tid & 127;       // channel

  // per-thread weight column pairs (wf_k, ws_k) in registers -> v_pk_fma_f32
  f32x2 wv[16];
#pragma unroll
  for (int k = 0; k < 16; ++k) {
    wv[k].x = fw3[k * HH + j];
    wv[k].y = sw3[k * HH + j];
  }

  const int e0 = blockIdx.x * EB;
  for (int i = tid; i < EB * 16; i += 256) {
    int le = i >> 4, k = i & 15;
    float d = eattr[e0 + le];
    float t = d - (float)k * GS_STEP;
    es[le][k] = __expf(GS_COEFF * t * t);
  }
  if (tid < EB) sd[tid] = make_int2(ei[e0 + tid], ei[NE + e0 + tid]);
  __syncthreads();

  const int half = tid >> 7;  // which of 2 edges per iteration
  for (int it = 0; it < EB / 2; ++it) {
    const int le = 2 * it + half;
    const int2 se = sd[le];                       // b64 broadcast
    const float4 g0 = *(const float4*)&es[le][0]; // b128 broadcasts
    const float4 g1 = *(const float4*)&es[le][4];
    const float4 g2 = *(const float4*)&es[le][8];
    const float4 g3 = *(const float4*)&es[le][12];
    const f32x2 a = *(const f32x2*)&PD[se.y * 256 + 2 * j];
    const f32x2 b = *(const f32x2*)&PS[se.x * 256 + 2 * j];
    f32x2 fs = a + b;   // (f, s) accumulated with packed math
    fs = __builtin_elementwise_fma((f32x2)(g0.x), wv[0],  fs);
    fs = __builtin_elementwise_fma((f32x2)(g0.y), wv[1],  fs);
    fs = __builtin_elementwise_fma((f32x2)(g0.z), wv[2],  fs);
    fs = __builtin_elementwise_fma((f32x2)(g0.w), wv[3],  fs);
    fs = __builtin_elementwise_fma((f32x2)(g1.x), wv[4],  fs);
    fs = __builtin_elementwise_fma((f32x2)(g1.y), wv[5],  fs);
    fs = __builtin_elementwise_fma((f32x2)(g1.z), wv[6],  fs);
    fs = __builtin_elementwise_fma((f32x2)(g1.w), wv[7],  fs);
    fs = __builtin_elementwise_fma((f32x2)(g2.x), wv[8],  fs);
    fs = __builtin_elementwise_fma((f32x2)(g2.y), wv[9],  fs);
    fs = __builtin_elementwise_fma((f32x2)(g2.z), wv[10], fs);
    fs = __builtin_elementwise_fma((f32x2)(g2.w), wv[11], fs);
    fs = __builtin_elementwise_fma((f32x2)(g3.x), wv[12], fs);
    fs = __builtin_elementwise_fma((f32x2)(g3.y), wv[13], fs);
    fs = __builtin_elementwise_fma((f32x2)(g3.z), wv[14], fs);
    fs = __builtin_elementwise_fma((f32x2)(g3.w), wv[15], fs);
    const float f = fs.x, s = fs.y;
    // sigmoid(f) = rcp(1 + 2^(-f*log2e)), all native v_exp/v_rcp
    const float ef = __builtin_amdgcn_exp2f(-f * LOG2E);
    const float sig = __builtin_amdgcn_rcpf(1.f + ef);
    // softplus(s) = max(s,0) + ln2 * log2(1 + 2^(-|s|*log2e)), native v_exp/v_log
    const float et = __builtin_amdgcn_exp2f(-fabsf(s) * LOG2E);
    const float sp = fmaxf(s, 0.f) + LN2 * __builtin_amdgcn_logf(1.f + et);
    atomicAdd(&agg[se.y * HH + j], sig * sp);
  }
}

// ---------------- per-channel sum / sumsq ----------------
__global__ __launch_bounds__(256) void k_stats(
    const float* __restrict__ agg, float* __restrict__ stats) {
  const int c = threadIdx.x & 127;
  const int slice = (blockIdx.x * 256 + threadIdx.x) >> 7;
  const int nslices = (gridDim.x * 256) >> 7;
  float s = 0.f, s2 = 0.f;
  for (int n = slice; n < NN; n += nslices) {
    float v = agg[n * HH + c];
    s += v;
    s2 = fmaf(v, v, s2);
  }
  atomicAdd(&stats[c], s);
  atomicAdd(&stats[HH + c], s2);
}

// ---------------- batchnorm + residual + relu ----------------
__global__ __launch_bounds__(256) void k_bn(
    const float* __restrict__ agg, const float* __restrict__ hold,
    const float* __restrict__ stats, const float* __restrict__ g,
    const float* __restrict__ b, float* __restrict__ hnew) {
  int t = blockIdx.x * 256 + threadIdx.x;
  if (t >= NH) return;
  const int c = t & 127;
  const float inv_n = 1.f / (float)NN;
  const float mu = stats[c] * inv_n;
  const float var = stats[HH + c] * inv_n - mu * mu;
  const float rs = rsqrtf(var + 1e-5f);
  const float v = (agg[t] - mu) * rs * g[c] + b[c] + hold[t];
  hnew[t] = fmaxf(v, 0.f);
}

// ---------------- final fc: out = h @ fc_w + fc_b ----------------
__global__ __launch_bounds__(64) void k_fc(
    const float* __restrict__ h, const float* __restrict__ w,
    const float* __restrict__ b, float* __restrict__ out) {
  const int ln = threadIdx.x >> 5;
  const int m = threadIdx.x & 31;
  const int n = blockIdx.x * 2 + ln;
  if (n >= NN || m >= 21) return;
  const float* hr = h + n * HH;
  float acc = b[m];
#pragma unroll 4
  for (int k = 0; k < HH; ++k) acc = fmaf(hr[k], w[k * 21 + m], acc);
  out[n * 21 + m] = acc;
}

extern "C" void kernel_launch(void* const* d_in, const int* in_sizes, int n_in,
                              void* d_out, int out_size, void* d_ws, size_t ws_size,
                              hipStream_t stream) {
  const float* x      = (const float*)d_in[0];
  const float* eattr  = (const float*)d_in[1];
  const float* node_w = (const float*)d_in[2];
  const float* node_b = (const float*)d_in[3];
  const float* f1w    = (const float*)d_in[4];
  const float* f1b    = (const float*)d_in[5];
  const float* s1w    = (const float*)d_in[6];
  const float* s1b    = (const float*)d_in[7];
  const float* bn1g   = (const float*)d_in[8];
  const float* bn1b   = (const float*)d_in[9];
  const float* f2w    = (const float*)d_in[10];
  const float* f2b    = (const float*)d_in[11];
  const float* s2w    = (const float*)d_in[12];
  const float* s2b    = (const float*)d_in[13];
  const float* bn2g   = (const float*)d_in[14];
  const float* bn2b   = (const float*)d_in[15];
  const float* fcw    = (const float*)d_in[16];
  const float* fcb    = (const float*)d_in[17];
  const int*   ei     = (const int*)d_in[18];
  float* out = (float*)d_out;

  float* ws   = (float*)d_ws;
  float* bufA = ws;            // h (layer input), later agg2/h2
  float* bufB = ws + NH;       // agg1 -> h1
  float* PD   = ws + 2 * (size_t)NH;  // [NN][256]
  float* PS   = ws + 4 * (size_t)NH;  // [NN][256]
  float* stats = ws + 6 * (size_t)NH; // 256 floats

  const int g_embed = (NH + 255) / 256;
  const int g_proj  = (NN + NB - 1) / NB;
  const int g_edge  = NE / EB;
  const int g_bn    = (NH + 255) / 256;

  // h0 = x @ node_w + node_b
  k_node_embed<<<g_embed, 256, 0, stream>>>(x, node_w, node_b, bufA);

  // ---- layer 1 ----
  k_proj<<<g_proj, 512, 0, stream>>>(bufA, f1w, s1w, f1b, s1b, PD, PS);
  hipMemsetAsync(bufB, 0, (size_t)NH * 4, stream);
  hipMemsetAsync(stats, 0, 256 * 4, stream);
  k_edge<<<g_edge, 256, 0, stream>>>(ei, eattr, f1w + 256 * HH, s1w + 256 * HH,
                                     PD, PS, bufB);
  k_stats<<<256, 256, 0, stream>>>(bufB, stats);
  k_bn<<<g_bn, 256, 0, stream>>>(bufB, bufA, stats, bn1g, bn1b, bufB);

  // ---- layer 2 ----
  k_proj<<<g_proj, 512, 0, stream>>>(bufB, f2w, s2w, f2b, s2b, PD, PS);
  hipMemsetAsync(bufA, 0, (size_t)NH * 4, stream);
  hipMemsetAsync(stats, 0, 256 * 4, stream);
  k_edge<<<g_edge, 256, 0, stream>>>(ei, eattr, f2w + 256 * HH, s2w + 256 * HH,
                                     PD, PS, bufA);
  k_stats<<<256, 256, 0, stream>>>(bufA, stats);
  k_bn<<<g_bn, 256, 0, stream>>>(bufA, bufB, stats, bn2g, bn2b, bufA);

  // ---- final fc ----
  k_fc<<<(NN + 1) / 2, 64, 0, stream>>>(bufA, fcw, fcb, out);
}

// Round 5
// 502.181 us; speedup vs baseline: 1.3393x; 1.2549x over previous
//
#include <hip/hip_runtime.h>
#include <math.h>

#define NN 25000
#define NE 400000
#define HH 128
#define NH (NN*HH)
#define NB 16
#define EB 64

// gaussian smearing: offset_k = k*8/15, coeff = -0.5/(8/15)^2 = -1.7578125
#define GS_STEP  (8.0f/15.0f)
#define GS_COEFF (-1.7578125f)
#define LOG2E    1.442695041f
#define LN2      0.6931471806f

typedef float f32x2 __attribute__((ext_vector_type(2)));

// ---------------- node embedding: h = x @ node_w + node_b ----------------
__global__ __launch_bounds__(256) void k_node_embed(
    const float* __restrict__ x, const float* __restrict__ w,
    const float* __restrict__ b, float* __restrict__ h) {
  int t = blockIdx.x * 256 + threadIdx.x;
  if (t >= NH) return;
  int n = t >> 7, j = t & 127;
  const float* xr = x + n * 6;
  float acc = b[j];
#pragma unroll
  for (int k = 0; k < 6; ++k) acc = fmaf(xr[k], w[k * HH + j], acc);
  h[t] = acc;
}

// ---------------- per-node projections (interleaved f/s) ----------------
__global__ __launch_bounds__(512) void k_proj(
    const float* __restrict__ h,
    const float* __restrict__ fw, const float* __restrict__ sw,
    const float* __restrict__ fb, const float* __restrict__ sb,
    float* __restrict__ PD, float* __restrict__ PS) {
  __shared__ float hs[NB * HH];
  const int tid = threadIdx.x;
  const int n0 = blockIdx.x * NB;
#pragma unroll
  for (int i = tid; i < NB * HH; i += 512) {
    int ln = i >> 7, k = i & 127;
    int n = n0 + ln;
    hs[ln * HH + k] = (n < NN) ? h[n * HH + k] : 0.f;
  }
  __syncthreads();
  const int p = tid >> 7;      // 0: f-dst, 1: f-src, 2: s-dst, 3: s-src
  const int j = tid & 127;
  const float* wb = ((p & 2) ? sw : fw) + ((p & 1) ? HH * HH : 0) + j;
  float acc[NB];
#pragma unroll
  for (int i = 0; i < NB; ++i) acc[i] = 0.f;
  for (int k0 = 0; k0 < HH; k0 += 4) {
    float w0 = wb[(k0 + 0) * HH];
    float w1 = wb[(k0 + 1) * HH];
    float w2 = wb[(k0 + 2) * HH];
    float w3 = wb[(k0 + 3) * HH];
#pragma unroll
    for (int i = 0; i < NB; ++i) {
      const float4 v = *(const float4*)(hs + i * HH + k0);
      acc[i] = fmaf(v.x, w0, acc[i]);
      acc[i] = fmaf(v.y, w1, acc[i]);
      acc[i] = fmaf(v.z, w2, acc[i]);
      acc[i] = fmaf(v.w, w3, acc[i]);
    }
  }
  const float bias = (p == 0) ? fb[j] : (p == 2) ? sb[j] : 0.f;
  float* outp = (p & 1) ? PS : PD;
  const int col = 2 * j + (p >> 1);
#pragma unroll
  for (int i = 0; i < NB; ++i) {
    int n = n0 + i;
    if (n < NN) outp[n * 256 + col] = acc[i] + bias;
  }
}

// ---------------- counting sort of edges by dst ----------------
__global__ __launch_bounds__(256) void k_hist(
    const int* __restrict__ ei, int* __restrict__ deg) {
  int e = blockIdx.x * 256 + threadIdx.x;
  if (e < NE) atomicAdd(&deg[ei[NE + e]], 1);
}

__global__ __launch_bounds__(1024) void k_scan(
    const int* __restrict__ deg, int* __restrict__ cursor) {
  __shared__ int part[1024];
  const int tid = threadIdx.x;
  const int CH = (NN + 1023) / 1024;  // 25
  const int base = tid * CH;
  int s = 0;
  for (int i = 0; i < CH; ++i) {
    int n = base + i;
    if (n < NN) s += deg[n];
  }
  part[tid] = s;
  __syncthreads();
  for (int off = 1; off < 1024; off <<= 1) {
    int t = (tid >= off) ? part[tid - off] : 0;
    __syncthreads();
    part[tid] += t;
    __syncthreads();
  }
  int run = part[tid] - s;  // exclusive prefix of this thread's chunk
  for (int i = 0; i < CH; ++i) {
    int n = base + i;
    if (n < NN) {
      cursor[n] = run;
      run += deg[n];
    }
  }
}

__global__ __launch_bounds__(256) void k_scatter(
    const int* __restrict__ ei, const float* __restrict__ eattr,
    int* __restrict__ cursor, int* __restrict__ esrc_s,
    int* __restrict__ edst_s, float* __restrict__ attr_s) {
  int e = blockIdx.x * 256 + threadIdx.x;
  if (e >= NE) return;
  const int dst = ei[NE + e];
  const int pos = atomicAdd(&cursor[dst], 1);
  esrc_s[pos] = ei[e];
  edst_s[pos] = dst;
  attr_s[pos] = eattr[e];
}

// ---------------- sorted edge kernel: register run-accumulation ----------------
__global__ __launch_bounds__(256) void k_edge_sorted(
    const int* __restrict__ esrc_s, const int* __restrict__ edst_s,
    const float* __restrict__ attr_s,
    const float* __restrict__ fw3, const float* __restrict__ sw3,
    const float* __restrict__ PD, const float* __restrict__ PS,
    float* __restrict__ agg) {
  __shared__ float gs[EB][16];
  __shared__ int ssrc[EB];
  __shared__ int sdst[EB + 1];
  const int tid = threadIdx.x;
  const int j = tid & 127;

  // (wf_k, ws_k) column pairs in registers -> v_pk_fma_f32
  f32x2 wv[16];
#pragma unroll
  for (int k = 0; k < 16; ++k) {
    wv[k].x = fw3[k * HH + j];
    wv[k].y = sw3[k * HH + j];
  }

  const int e0 = blockIdx.x * EB;
  if (tid < EB) ssrc[tid] = esrc_s[e0 + tid];
  else if (tid < 2 * EB) sdst[tid - EB] = edst_s[e0 + tid - EB];
  for (int i = tid; i < EB * 16; i += 256) {
    int le = i >> 4, k = i & 15;
    float d = attr_s[e0 + le];
    float t = d - (float)k * GS_STEP;
    gs[le][k] = __expf(GS_COEFF * t * t);
  }
  __syncthreads();

  const int half = tid >> 7;
  const int lbase = half * 32;
  float macc = 0.f;
  int cur = -1;
  f32x2 a = 0.f;
  f32x2 b = *(const f32x2*)&PS[ssrc[lbase] * 256 + 2 * j];  // pipeline preload
  for (int it = 0; it < 32; ++it) {
    const int le = lbase + it;
    const int dst = sdst[le];
    if (dst != cur) {  // wave-uniform branch: new dst run
      a = *(const f32x2*)&PD[dst * 256 + 2 * j];
      cur = dst;
    }
    const f32x2 bb = b;
    if (it < 31) b = *(const f32x2*)&PS[ssrc[le + 1] * 256 + 2 * j];
    const float4 g0 = *(const float4*)&gs[le][0];
    const float4 g1 = *(const float4*)&gs[le][4];
    const float4 g2 = *(const float4*)&gs[le][8];
    const float4 g3 = *(const float4*)&gs[le][12];
    f32x2 fs = a + bb;
    fs = __builtin_elementwise_fma((f32x2)(g0.x), wv[0],  fs);
    fs = __builtin_elementwise_fma((f32x2)(g0.y), wv[1],  fs);
    fs = __builtin_elementwise_fma((f32x2)(g0.z), wv[2],  fs);
    fs = __builtin_elementwise_fma((f32x2)(g0.w), wv[3],  fs);
    fs = __builtin_elementwise_fma((f32x2)(g1.x), wv[4],  fs);
    fs = __builtin_elementwise_fma((f32x2)(g1.y), wv[5],  fs);
    fs = __builtin_elementwise_fma((f32x2)(g1.z), wv[6],  fs);
    fs = __builtin_elementwise_fma((f32x2)(g1.w), wv[7],  fs);
    fs = __builtin_elementwise_fma((f32x2)(g2.x), wv[8],  fs);
    fs = __builtin_elementwise_fma((f32x2)(g2.y), wv[9],  fs);
    fs = __builtin_elementwise_fma((f32x2)(g2.z), wv[10], fs);
    fs = __builtin_elementwise_fma((f32x2)(g2.w), wv[11], fs);
    fs = __builtin_elementwise_fma((f32x2)(g3.x), wv[12], fs);
    fs = __builtin_elementwise_fma((f32x2)(g3.y), wv[13], fs);
    fs = __builtin_elementwise_fma((f32x2)(g3.z), wv[14], fs);
    fs = __builtin_elementwise_fma((f32x2)(g3.w), wv[15], fs);
    const float f = fs.x, s = fs.y;
    const float ef = __builtin_amdgcn_exp2f(-f * LOG2E);
    const float sig = __builtin_amdgcn_rcpf(1.f + ef);
    const float et = __builtin_amdgcn_exp2f(-fabsf(s) * LOG2E);
    const float sp = fmaxf(s, 0.f) + LN2 * __builtin_amdgcn_logf(1.f + et);
    macc = fmaf(sig, sp, macc);
    const bool fl = (it == 31) || (sdst[le + 1] != dst);
    if (fl) {  // wave-uniform: end of run -> single flush
      atomicAdd(&agg[dst * HH + j], macc);
      macc = 0.f;
    }
  }
}

// ---------------- per-channel sum / sumsq ----------------
__global__ __launch_bounds__(256) void k_stats(
    const float* __restrict__ agg, float* __restrict__ stats) {
  const int c = threadIdx.x & 127;
  const int slice = (blockIdx.x * 256 + threadIdx.x) >> 7;
  const int nslices = (gridDim.x * 256) >> 7;
  float s = 0.f, s2 = 0.f;
  for (int n = slice; n < NN; n += nslices) {
    float v = agg[n * HH + c];
    s += v;
    s2 = fmaf(v, v, s2);
  }
  atomicAdd(&stats[c], s);
  atomicAdd(&stats[HH + c], s2);
}

// ---------------- batchnorm + residual + relu ----------------
__global__ __launch_bounds__(256) void k_bn(
    const float* __restrict__ agg, const float* __restrict__ hold,
    const float* __restrict__ stats, const float* __restrict__ g,
    const float* __restrict__ b, float* __restrict__ hnew) {
  int t = blockIdx.x * 256 + threadIdx.x;
  if (t >= NH) return;
  const int c = t & 127;
  const float inv_n = 1.f / (float)NN;
  const float mu = stats[c] * inv_n;
  const float var = stats[HH + c] * inv_n - mu * mu;
  const float rs = rsqrtf(var + 1e-5f);
  const float v = (agg[t] - mu) * rs * g[c] + b[c] + hold[t];
  hnew[t] = fmaxf(v, 0.f);
}

// ---------------- final fc: out = h @ fc_w + fc_b ----------------
__global__ __launch_bounds__(64) void k_fc(
    const float* __restrict__ h, const float* __restrict__ w,
    const float* __restrict__ b, float* __restrict__ out) {
  const int ln = threadIdx.x >> 5;
  const int m = threadIdx.x & 31;
  const int n = blockIdx.x * 2 + ln;
  if (n >= NN || m >= 21) return;
  const float* hr = h + n * HH;
  float acc = b[m];
#pragma unroll 4
  for (int k = 0; k < HH; ++k) acc = fmaf(hr[k], w[k * 21 + m], acc);
  out[n * 21 + m] = acc;
}

extern "C" void kernel_launch(void* const* d_in, const int* in_sizes, int n_in,
                              void* d_out, int out_size, void* d_ws, size_t ws_size,
                              hipStream_t stream) {
  const float* x      = (const float*)d_in[0];
  const float* eattr  = (const float*)d_in[1];
  const float* node_w = (const float*)d_in[2];
  const float* node_b = (const float*)d_in[3];
  const float* f1w    = (const float*)d_in[4];
  const float* f1b    = (const float*)d_in[5];
  const float* s1w    = (const float*)d_in[6];
  const float* s1b    = (const float*)d_in[7];
  const float* bn1g   = (const float*)d_in[8];
  const float* bn1b   = (const float*)d_in[9];
  const float* f2w    = (const float*)d_in[10];
  const float* f2b    = (const float*)d_in[11];
  const float* s2w    = (const float*)d_in[12];
  const float* s2b    = (const float*)d_in[13];
  const float* bn2g   = (const float*)d_in[14];
  const float* bn2b   = (const float*)d_in[15];
  const float* fcw    = (const float*)d_in[16];
  const float* fcb    = (const float*)d_in[17];
  const int*   ei     = (const int*)d_in[18];
  float* out = (float*)d_out;

  float* ws   = (float*)d_ws;
  float* bufA = ws;                          // h0, later agg2/h2
  float* bufB = ws + NH;                     // agg1 -> h1
  float* PD   = ws + 2 * (size_t)NH;         // [NN][256]
  float* PS   = ws + 4 * (size_t)NH;         // [NN][256]
  float* stats = ws + 6 * (size_t)NH;        // 256 floats
  int*   deg    = (int*)(ws + 6 * (size_t)NH + 256);   // NN ints
  int*   cursor = deg + NN;                  // NN ints
  int*   esrc_s = cursor + NN;               // NE ints
  int*   edst_s = esrc_s + NE;               // NE ints
  float* attr_s = (float*)(edst_s + NE);     // NE floats

  const int g_embed = (NH + 255) / 256;
  const int g_proj  = (NN + NB - 1) / NB;
  const int g_edge  = NE / EB;
  const int g_bn    = (NH + 255) / 256;
  const int g_e256  = (NE + 255) / 256;

  // h0 = x @ node_w + node_b
  k_node_embed<<<g_embed, 256, 0, stream>>>(x, node_w, node_b, bufA);

  // ---- counting sort of edges by dst (reused by both layers) ----
  hipMemsetAsync(deg, 0, NN * 4, stream);
  k_hist<<<g_e256, 256, 0, stream>>>(ei, deg);
  k_scan<<<1, 1024, 0, stream>>>(deg, cursor);
  k_scatter<<<g_e256, 256, 0, stream>>>(ei, eattr, cursor, esrc_s, edst_s, attr_s);

  // ---- layer 1 ----
  k_proj<<<g_proj, 512, 0, stream>>>(bufA, f1w, s1w, f1b, s1b, PD, PS);
  hipMemsetAsync(bufB, 0, (size_t)NH * 4, stream);
  hipMemsetAsync(stats, 0, 256 * 4, stream);
  k_edge_sorted<<<g_edge, 256, 0, stream>>>(esrc_s, edst_s, attr_s,
                                            f1w + 256 * HH, s1w + 256 * HH,
                                            PD, PS, bufB);
  k_stats<<<256, 256, 0, stream>>>(bufB, stats);
  k_bn<<<g_bn, 256, 0, stream>>>(bufB, bufA, stats, bn1g, bn1b, bufB);

  // ---- layer 2 ----
  k_proj<<<g_proj, 512, 0, stream>>>(bufB, f2w, s2w, f2b, s2b, PD, PS);
  hipMemsetAsync(bufA, 0, (size_t)NH * 4, stream);
  hipMemsetAsync(stats, 0, 256 * 4, stream);
  k_edge_sorted<<<g_edge, 256, 0, stream>>>(esrc_s, edst_s, attr_s,
                                            f2w + 256 * HH, s2w + 256 * HH,
                                            PD, PS, bufA);
  k_stats<<<256, 256, 0, stream>>>(bufA, stats);
  k_bn<<<g_bn, 256, 0, stream>>>(bufA, bufB, stats, bn2g, bn2b, bufA);

  // ---- final fc ----
  k_fc<<<(NN + 1) / 2, 64, 0, stream>>>(bufA, fcw, fcb, out);
}

// Round 6
// 476.908 us; speedup vs baseline: 1.4103x; 1.0530x over previous
//
#include <hip/hip_runtime.h>
#include <math.h>

#define NN 25000
#define NE 400000
#define HH 128
#define NH (NN*HH)
#define EB 64

// gaussian smearing: offset_k = k*8/15, coeff = -0.5/(8/15)^2 = -1.7578125
#define GS_STEP  (8.0f/15.0f)
#define GS_COEFF (-1.7578125f)
#define LOG2E    1.442695041f
#define LN2      0.6931471806f

typedef float f32x2 __attribute__((ext_vector_type(2)));

// ---------------- node embedding: h = x @ node_w + node_b ----------------
__global__ __launch_bounds__(256) void k_node_embed(
    const float* __restrict__ x, const float* __restrict__ w,
    const float* __restrict__ b, float* __restrict__ h) {
  int t = blockIdx.x * 256 + threadIdx.x;
  if (t >= NH) return;
  int n = t >> 7, j = t & 127;
  const float* xr = x + n * 6;
  float acc = b[j];
#pragma unroll
  for (int k = 0; k < 6; ++k) acc = fmaf(xr[k], w[k * HH + j], acc);
  h[t] = acc;
}

// ---------------- weight repack: Wp[128][512] in interleaved PD/PS order ----
// col c<256:  PD col c = (c&1 ? sw : fw)[k][c>>1]            (+ bias)
// col c>=256: PS col (c-256) = (c&1 ? sw : fw)[128+k][(c-256)>>1]
__global__ __launch_bounds__(256) void k_pack(
    const float* __restrict__ fw, const float* __restrict__ sw,
    const float* __restrict__ fb, const float* __restrict__ sb,
    float* __restrict__ Wp, float* __restrict__ biasv) {
  int t = blockIdx.x * 256 + threadIdx.x;
  if (t < 512) biasv[t] = (t < 256) ? ((t & 1) ? sb[t >> 1] : fb[t >> 1]) : 0.f;
  if (t >= 128 * 512) return;
  const int k = t >> 9, c = t & 511;
  const int cc = c & 255;
  const int row = ((c >= 256) ? 128 : 0) + k;
  const float* m = (cc & 1) ? sw : fw;
  Wp[t] = m[row * HH + (cc >> 1)];
}

// ---------------- projection GEMM: C[NN x 512] = H[NN x 128] @ Wp --------
// 64 nodes x 128 cols per 256-thread block; 8m x 4n per thread.
__global__ __launch_bounds__(256) void k_gemm(
    const float* __restrict__ h, const float* __restrict__ Wp,
    const float* __restrict__ biasv,
    float* __restrict__ PD, float* __restrict__ PS) {
  __shared__ float ht[128][68];   // transposed tile, pad 68 (16B-aligned rows)
  const int tid = threadIdx.x;
  const int n0 = blockIdx.x * 64;
  const int bn0 = blockIdx.y * 128;
  for (int i = tid; i < 64 * 128; i += 256) {
    int ln = i >> 7, k = i & 127;
    int n = n0 + ln;
    ht[k][ln] = (n < NN) ? h[n * HH + k] : 0.f;
  }
  __syncthreads();
  const int tx = tid & 31, ty = tid >> 5;
  const int m0 = ty * 8;
  const float* wp = Wp + bn0 + 4 * tx;
  f32x2 acc[8][2];
#pragma unroll
  for (int mi = 0; mi < 8; ++mi) { acc[mi][0] = 0.f; acc[mi][1] = 0.f; }
  for (int k = 0; k < 128; ++k) {
    const float4 bv = *(const float4*)(wp + k * 512);
    const f32x2 b01 = {bv.x, bv.y}, b23 = {bv.z, bv.w};
    const float4 a0 = *(const float4*)&ht[k][m0];
    const float4 a1 = *(const float4*)&ht[k][m0 + 4];
    const float am[8] = {a0.x, a0.y, a0.z, a0.w, a1.x, a1.y, a1.z, a1.w};
#pragma unroll
    for (int mi = 0; mi < 8; ++mi) {
      acc[mi][0] = __builtin_elementwise_fma((f32x2)(am[mi]), b01, acc[mi][0]);
      acc[mi][1] = __builtin_elementwise_fma((f32x2)(am[mi]), b23, acc[mi][1]);
    }
  }
  const float4 bias4 = *(const float4*)(biasv + bn0 + 4 * tx);
  const f32x2 bb01 = {bias4.x, bias4.y}, bb23 = {bias4.z, bias4.w};
  float* basep = (bn0 < 256) ? PD : PS;
  const int cb = ((bn0 < 256) ? bn0 : bn0 - 256) + 4 * tx;
#pragma unroll
  for (int mi = 0; mi < 8; ++mi) {
    const int n = n0 + m0 + mi;
    if (n < NN) {
      const f32x2 r0 = acc[mi][0] + bb01;
      const f32x2 r1 = acc[mi][1] + bb23;
      float4 st = {r0.x, r0.y, r1.x, r1.y};
      *(float4*)&basep[n * 256 + cb] = st;
    }
  }
}

// ---------------- counting sort of edges by dst ----------------
__global__ __launch_bounds__(256) void k_hist(
    const int* __restrict__ ei, int* __restrict__ deg) {
  int e = blockIdx.x * 256 + threadIdx.x;
  if (e < NE) atomicAdd(&deg[ei[NE + e]], 1);
}

__global__ __launch_bounds__(1024) void k_scan(
    const int* __restrict__ deg, int* __restrict__ cursor) {
  __shared__ int part[1024];
  const int tid = threadIdx.x;
  const int CH = (NN + 1023) / 1024;  // 25
  const int base = tid * CH;
  int s = 0;
  for (int i = 0; i < CH; ++i) {
    int n = base + i;
    if (n < NN) s += deg[n];
  }
  part[tid] = s;
  __syncthreads();
  for (int off = 1; off < 1024; off <<= 1) {
    int t = (tid >= off) ? part[tid - off] : 0;
    __syncthreads();
    part[tid] += t;
    __syncthreads();
  }
  int run = part[tid] - s;
  for (int i = 0; i < CH; ++i) {
    int n = base + i;
    if (n < NN) {
      cursor[n] = run;
      run += deg[n];
    }
  }
}

__global__ __launch_bounds__(256) void k_scatter(
    const int* __restrict__ ei, const float* __restrict__ eattr,
    int* __restrict__ cursor, int* __restrict__ esrc_s,
    int* __restrict__ edst_s, float* __restrict__ attr_s) {
  int e = blockIdx.x * 256 + threadIdx.x;
  if (e >= NE) return;
  const int dst = ei[NE + e];
  const int pos = atomicAdd(&cursor[dst], 1);
  esrc_s[pos] = ei[e];
  edst_s[pos] = dst;
  attr_s[pos] = eattr[e];
}

// ---------------- sorted edge kernel: register run-accumulation ----------------
__global__ __launch_bounds__(256) void k_edge_sorted(
    const int* __restrict__ esrc_s, const int* __restrict__ edst_s,
    const float* __restrict__ attr_s,
    const float* __restrict__ fw3, const float* __restrict__ sw3,
    const float* __restrict__ PD, const float* __restrict__ PS,
    float* __restrict__ agg) {
  __shared__ float gs[EB][16];
  __shared__ int ssrc[EB];
  __shared__ int sdst[EB + 1];
  const int tid = threadIdx.x;
  const int j = tid & 127;

  f32x2 wv[16];
#pragma unroll
  for (int k = 0; k < 16; ++k) {
    wv[k].x = fw3[k * HH + j];
    wv[k].y = sw3[k * HH + j];
  }

  const int e0 = blockIdx.x * EB;
  if (tid < EB) ssrc[tid] = esrc_s[e0 + tid];
  else if (tid < 2 * EB) sdst[tid - EB] = edst_s[e0 + tid - EB];
  for (int i = tid; i < EB * 16; i += 256) {
    int le = i >> 4, k = i & 15;
    float d = attr_s[e0 + le];
    float t = d - (float)k * GS_STEP;
    gs[le][k] = __expf(GS_COEFF * t * t);
  }
  __syncthreads();

  const int half = tid >> 7;
  const int lbase = half * 32;
  float macc = 0.f;
  int cur = -1;
  f32x2 a = 0.f;
  f32x2 b = *(const f32x2*)&PS[ssrc[lbase] * 256 + 2 * j];
  for (int it = 0; it < 32; ++it) {
    const int le = lbase + it;
    const int dst = sdst[le];
    if (dst != cur) {
      a = *(const f32x2*)&PD[dst * 256 + 2 * j];
      cur = dst;
    }
    const f32x2 bb = b;
    if (it < 31) b = *(const f32x2*)&PS[ssrc[le + 1] * 256 + 2 * j];
    const float4 g0 = *(const float4*)&gs[le][0];
    const float4 g1 = *(const float4*)&gs[le][4];
    const float4 g2 = *(const float4*)&gs[le][8];
    const float4 g3 = *(const float4*)&gs[le][12];
    f32x2 fs = a + bb;
    fs = __builtin_elementwise_fma((f32x2)(g0.x), wv[0],  fs);
    fs = __builtin_elementwise_fma((f32x2)(g0.y), wv[1],  fs);
    fs = __builtin_elementwise_fma((f32x2)(g0.z), wv[2],  fs);
    fs = __builtin_elementwise_fma((f32x2)(g0.w), wv[3],  fs);
    fs = __builtin_elementwise_fma((f32x2)(g1.x), wv[4],  fs);
    fs = __builtin_elementwise_fma((f32x2)(g1.y), wv[5],  fs);
    fs = __builtin_elementwise_fma((f32x2)(g1.z), wv[6],  fs);
    fs = __builtin_elementwise_fma((f32x2)(g1.w), wv[7],  fs);
    fs = __builtin_elementwise_fma((f32x2)(g2.x), wv[8],  fs);
    fs = __builtin_elementwise_fma((f32x2)(g2.y), wv[9],  fs);
    fs = __builtin_elementwise_fma((f32x2)(g2.z), wv[10], fs);
    fs = __builtin_elementwise_fma((f32x2)(g2.w), wv[11], fs);
    fs = __builtin_elementwise_fma((f32x2)(g3.x), wv[12], fs);
    fs = __builtin_elementwise_fma((f32x2)(g3.y), wv[13], fs);
    fs = __builtin_elementwise_fma((f32x2)(g3.z), wv[14], fs);
    fs = __builtin_elementwise_fma((f32x2)(g3.w), wv[15], fs);
    const float f = fs.x, s = fs.y;
    const float ef = __builtin_amdgcn_exp2f(-f * LOG2E);
    const float sig = __builtin_amdgcn_rcpf(1.f + ef);
    const float et = __builtin_amdgcn_exp2f(-fabsf(s) * LOG2E);
    const float sp = fmaxf(s, 0.f) + LN2 * __builtin_amdgcn_logf(1.f + et);
    macc = fmaf(sig, sp, macc);
    const bool fl = (it == 31) || (sdst[le + 1] != dst);
    if (fl) {
      atomicAdd(&agg[dst * HH + j], macc);
      macc = 0.f;
    }
  }
}

// ---------------- per-channel sum / sumsq ----------------
__global__ __launch_bounds__(256) void k_stats(
    const float* __restrict__ agg, float* __restrict__ stats) {
  const int c = threadIdx.x & 127;
  const int slice = (blockIdx.x * 256 + threadIdx.x) >> 7;
  const int nslices = (gridDim.x * 256) >> 7;
  float s = 0.f, s2 = 0.f;
  for (int n = slice; n < NN; n += nslices) {
    float v = agg[n * HH + c];
    s += v;
    s2 = fmaf(v, v, s2);
  }
  atomicAdd(&stats[c], s);
  atomicAdd(&stats[HH + c], s2);
}

// ---------------- batchnorm + residual + relu ----------------
__global__ __launch_bounds__(256) void k_bn(
    const float* __restrict__ agg, const float* __restrict__ hold,
    const float* __restrict__ stats, const float* __restrict__ g,
    const float* __restrict__ b, float* __restrict__ hnew) {
  int t = blockIdx.x * 256 + threadIdx.x;
  if (t >= NH) return;
  const int c = t & 127;
  const float inv_n = 1.f / (float)NN;
  const float mu = stats[c] * inv_n;
  const float var = stats[HH + c] * inv_n - mu * mu;
  const float rs = rsqrtf(var + 1e-5f);
  const float v = (agg[t] - mu) * rs * g[c] + b[c] + hold[t];
  hnew[t] = fmaxf(v, 0.f);
}

// ---------------- final fc: out = h @ fc_w + fc_b ----------------
__global__ __launch_bounds__(64) void k_fc(
    const float* __restrict__ h, const float* __restrict__ w,
    const float* __restrict__ b, float* __restrict__ out) {
  const int ln = threadIdx.x >> 5;
  const int m = threadIdx.x & 31;
  const int n = blockIdx.x * 2 + ln;
  if (n >= NN || m >= 21) return;
  const float* hr = h + n * HH;
  float acc = b[m];
#pragma unroll 4
  for (int k = 0; k < HH; ++k) acc = fmaf(hr[k], w[k * 21 + m], acc);
  out[n * 21 + m] = acc;
}

extern "C" void kernel_launch(void* const* d_in, const int* in_sizes, int n_in,
                              void* d_out, int out_size, void* d_ws, size_t ws_size,
                              hipStream_t stream) {
  const float* x      = (const float*)d_in[0];
  const float* eattr  = (const float*)d_in[1];
  const float* node_w = (const float*)d_in[2];
  const float* node_b = (const float*)d_in[3];
  const float* f1w    = (const float*)d_in[4];
  const float* f1b    = (const float*)d_in[5];
  const float* s1w    = (const float*)d_in[6];
  const float* s1b    = (const float*)d_in[7];
  const float* bn1g   = (const float*)d_in[8];
  const float* bn1b   = (const float*)d_in[9];
  const float* f2w    = (const float*)d_in[10];
  const float* f2b    = (const float*)d_in[11];
  const float* s2w    = (const float*)d_in[12];
  const float* s2b    = (const float*)d_in[13];
  const float* bn2g   = (const float*)d_in[14];
  const float* bn2b   = (const float*)d_in[15];
  const float* fcw    = (const float*)d_in[16];
  const float* fcb    = (const float*)d_in[17];
  const int*   ei     = (const int*)d_in[18];
  float* out = (float*)d_out;

  float* ws   = (float*)d_ws;
  float* bufA = ws;                          // h0, later agg2/h2
  float* bufB = ws + NH;                     // agg1 -> h1
  float* PD   = ws + 2 * (size_t)NH;         // [NN][256]
  float* PS   = ws + 4 * (size_t)NH;         // [NN][256]
  float* stats = ws + 6 * (size_t)NH;        // 256 floats
  int*   deg    = (int*)(ws + 6 * (size_t)NH + 256);   // NN ints
  int*   cursor = deg + NN;                  // NN ints
  int*   esrc_s = cursor + NN;               // NE ints
  int*   edst_s = esrc_s + NE;               // NE ints
  float* attr_s = (float*)(edst_s + NE);     // NE floats
  float* Wp     = attr_s + NE;               // 128*512 floats
  float* biasv  = Wp + 128 * 512;            // 512 floats

  const int g_embed = (NH + 255) / 256;
  const int g_edge  = NE / EB;
  const int g_bn    = (NH + 255) / 256;
  const int g_e256  = (NE + 255) / 256;
  const dim3 g_gemm((NN + 63) / 64, 4);

  // h0 = x @ node_w + node_b
  k_node_embed<<<g_embed, 256, 0, stream>>>(x, node_w, node_b, bufA);

  // ---- counting sort of edges by dst (reused by both layers) ----
  hipMemsetAsync(deg, 0, NN * 4, stream);
  k_hist<<<g_e256, 256, 0, stream>>>(ei, deg);
  k_scan<<<1, 1024, 0, stream>>>(deg, cursor);
  k_scatter<<<g_e256, 256, 0, stream>>>(ei, eattr, cursor, esrc_s, edst_s, attr_s);

  // ---- layer 1 ----
  k_pack<<<256, 256, 0, stream>>>(f1w, s1w, f1b, s1b, Wp, biasv);
  k_gemm<<<g_gemm, 256, 0, stream>>>(bufA, Wp, biasv, PD, PS);
  hipMemsetAsync(bufB, 0, (size_t)NH * 4, stream);
  hipMemsetAsync(stats, 0, 256 * 4, stream);
  k_edge_sorted<<<g_edge, 256, 0, stream>>>(esrc_s, edst_s, attr_s,
                                            f1w + 256 * HH, s1w + 256 * HH,
                                            PD, PS, bufB);
  k_stats<<<256, 256, 0, stream>>>(bufB, stats);
  k_bn<<<g_bn, 256, 0, stream>>>(bufB, bufA, stats, bn1g, bn1b, bufB);

  // ---- layer 2 ----
  k_pack<<<256, 256, 0, stream>>>(f2w, s2w, f2b, s2b, Wp, biasv);
  k_gemm<<<g_gemm, 256, 0, stream>>>(bufB, Wp, biasv, PD, PS);
  hipMemsetAsync(bufA, 0, (size_t)NH * 4, stream);
  hipMemsetAsync(stats, 0, 256 * 4, stream);
  k_edge_sorted<<<g_edge, 256, 0, stream>>>(esrc_s, edst_s, attr_s,
                                            f2w + 256 * HH, s2w + 256 * HH,
                                            PD, PS, bufA);
  k_stats<<<256, 256, 0, stream>>>(bufA, stats);
  k_bn<<<g_bn, 256, 0, stream>>>(bufA, bufB, stats, bn2g, bn2b, bufA);

  // ---- final fc ----
  k_fc<<<(NN + 1) / 2, 64, 0, stream>>>(bufA, fcw, fcb, out);
}